// Round 4
// baseline (208.573 us; speedup 1.0000x reference)
//
#include <hip/hip_runtime.h>
#include <hip/hip_bf16.h>

typedef __attribute__((ext_vector_type(8))) _Float16 f16x8;
typedef __attribute__((ext_vector_type(4))) _Float16 f16x4;
typedef __attribute__((ext_vector_type(4))) float f32x4;

#define D 128
#define NCH 256   // Pab channels: [0:128)=Pa'=Pa+b1, [128:256)=Pb

static __device__ __forceinline__ ushort f2h(float f) {
    _Float16 h = (_Float16)f;
    return __builtin_bit_cast(ushort, h);
}

// ---------- prep: w1abt fp16 [oc][k] (oc<128: W1a=W1top-W1bot; oc>=128: W1b), w2t fp16, col histogram
__global__ void prep_kernel(const float* __restrict__ W1,
                            const float* __restrict__ W2,
                            const int* __restrict__ ecol,
                            ushort* __restrict__ w1abt,
                            ushort* __restrict__ w2t,
                            int* __restrict__ hist,
                            int E, int n_nodes)
{
    int gid = blockIdx.x * blockDim.x + threadIdx.x;
    if (gid < NCH * D) {
        int oc = gid >> 7, k = gid & 127;
        float v;
        if (oc < 128) v = W1[k * D + oc] - W1[(k + 128) * D + oc];
        else          v = W1[(k + 128) * D + (oc - 128)];
        w1abt[gid] = f2h(v);
    } else if (gid < NCH * D + D * D) {
        int id2 = gid - NCH * D;
        int oc = id2 >> 7, k = id2 & 127;
        w2t[id2] = f2h(W2[k * D + oc]);
    } else {
        int e = gid - (NCH * D + D * D);
        if (e < E) {
            int c = ecol[e];
            if ((unsigned)c >= (unsigned)n_nodes) c = 0;
            atomicAdd(&hist[c], 1);
        }
    }
}

// ---------- Pab = x(fp16) @ [W1a | W1b] (+b1 folded into Pa'), fp16 out
__global__ __launch_bounds__(256) void pab_kernel(
    const float* __restrict__ x,
    const ushort* __restrict__ w1abt,
    const float* __restrict__ b1,
    ushort* __restrict__ pab,
    int n_nodes)
{
    __shared__ ushort A[64 * 128];   // [node][k] fp16, swizzled
    const int tid = threadIdx.x;
    const int base = blockIdx.x * 64;

    #pragma unroll
    for (int it = 0; it < 8; ++it) {
        int idx4 = it * 256 + tid;       // float4 index in 64x128 tile
        int row = idx4 >> 5;
        int c4  = idx4 & 31;
        int node = base + row;
        float4 v = make_float4(0.f, 0.f, 0.f, 0.f);
        if (node < n_nodes) v = ((const float4*)x)[(size_t)node * 32 + c4];
        f16x4 o;
        o[0] = (_Float16)v.x; o[1] = (_Float16)v.y;
        o[2] = (_Float16)v.z; o[3] = (_Float16)v.w;
        *(f16x4*)((char*)A + row * 256 + ((c4 * 8) ^ ((row & 7) << 4))) = o;
    }
    __syncthreads();

    const int l = tid & 63, w = tid >> 6;
    const int l15 = l & 15, lq = l >> 4;

    f32x4 acc[4][4];                 // [channel frag][node frag]
    #pragma unroll
    for (int cf = 0; cf < 4; ++cf)
        #pragma unroll
        for (int rf = 0; rf < 4; ++rf)
            acc[cf][rf] = (f32x4){0.f, 0.f, 0.f, 0.f};

    #pragma unroll
    for (int kk = 0; kk < 4; ++kk) {
        f16x8 a[4], b[4];
        #pragma unroll
        for (int cf = 0; cf < 4; ++cf)
            a[cf] = *(const f16x8*)(w1abt + (w * 64 + cf * 16 + l15) * 128 + kk * 32 + lq * 8);
        #pragma unroll
        for (int rf = 0; rf < 4; ++rf) {
            int row = rf * 16 + l15;
            b[rf] = *(const f16x8*)((const char*)A + row * 256 + ((kk * 64 + lq * 16) ^ ((row & 7) << 4)));
        }
        #pragma unroll
        for (int cf = 0; cf < 4; ++cf)
            #pragma unroll
            for (int rf = 0; rf < 4; ++rf)
                acc[cf][rf] = __builtin_amdgcn_mfma_f32_16x16x32_f16(a[cf], b[rf], acc[cf][rf], 0, 0, 0);
    }

    // D[ch][node]: node = rf*16 + l15 (lane), ch = w*64 + cf*16 + lq*4 + r
    #pragma unroll
    for (int rf = 0; rf < 4; ++rf) {
        int node = base + rf * 16 + l15;
        if (node < n_nodes) {
            #pragma unroll
            for (int cf = 0; cf < 4; ++cf) {
                int ch = w * 64 + cf * 16 + lq * 4;
                float4 bb = (w < 2) ? *(const float4*)(b1 + ch) : make_float4(0.f, 0.f, 0.f, 0.f);
                f16x4 o;
                o[0] = (_Float16)(acc[cf][rf][0] + bb.x);
                o[1] = (_Float16)(acc[cf][rf][1] + bb.y);
                o[2] = (_Float16)(acc[cf][rf][2] + bb.z);
                o[3] = (_Float16)(acc[cf][rf][3] + bb.w);
                *(f16x4*)(pab + (size_t)node * NCH + ch) = o;
            }
        }
    }
}

// ---------- hierarchical exclusive scan (coalesced)
__global__ void scan1_kernel(const int* __restrict__ hist, int* __restrict__ partial, int N)
{
    __shared__ int s[256];
    int tid = threadIdx.x;
    int i = blockIdx.x * 256 + tid;
    s[tid] = (i < N) ? hist[i] : 0;
    __syncthreads();
    #pragma unroll
    for (int off = 128; off > 0; off >>= 1) {
        if (tid < off) s[tid] += s[tid + off];
        __syncthreads();
    }
    if (tid == 0) partial[blockIdx.x] = s[0];
}

__global__ void scan2_kernel(const int* __restrict__ partial, int* __restrict__ bofs, int nb)
{
    __shared__ int s[256];
    int tid = threadIdx.x;
    int v = (tid < nb) ? partial[tid] : 0;
    s[tid] = v;
    __syncthreads();
    #pragma unroll
    for (int off = 1; off < 256; off <<= 1) {
        int t = (tid >= off) ? s[tid - off] : 0;
        __syncthreads();
        s[tid] += t;
        __syncthreads();
    }
    if (tid < nb) bofs[tid] = s[tid] - v;
}

__global__ void scan3_kernel(const int* __restrict__ hist, const int* __restrict__ bofs,
                             int* __restrict__ ofs, int N)
{
    __shared__ int s[256];
    int tid = threadIdx.x;
    int i = blockIdx.x * 256 + tid;
    int v = (i < N) ? hist[i] : 0;
    s[tid] = v;
    __syncthreads();
    #pragma unroll
    for (int off = 1; off < 256; off <<= 1) {
        int t = (tid >= off) ? s[tid - off] : 0;
        __syncthreads();
        s[tid] += t;
        __syncthreads();
    }
    if (i < N) ofs[i] = bofs[blockIdx.x] + s[tid] - v;
}

// ---------- scatter: counting sort; emit (col,row) int2 pairs (one 8B store)
__global__ void scatter_kernel(const int* __restrict__ erow, const int* __restrict__ ecol,
                               int* __restrict__ ofs,
                               int2* __restrict__ spair,
                               int E, int n_nodes)
{
    int e = blockIdx.x * blockDim.x + threadIdx.x;
    if (e < E) {
        int c = ecol[e];
        if ((unsigned)c >= (unsigned)n_nodes) c = 0;
        int r = erow[e];
        if ((unsigned)r >= (unsigned)n_nodes) r = 0;
        int pos = atomicAdd(&ofs[c], 1);
        spair[pos] = make_int2(c, r);
    }
}

// ---------- main fused kernel: 64 sorted edges per block, 256 threads (4 waves, 2x2)
__global__ __launch_bounds__(256, 4) void edgeconv_main(
    const ushort* __restrict__ pab,
    const ushort* __restrict__ w2t,
    const int2* __restrict__ spair,
    unsigned int* __restrict__ out_enc,
    int E, int n_nodes)
{
    __shared__ char smem[64 * 256];     // 16KB: Hs fp16[64][128] (swizzled), then Mf f32[64][64] halves
    __shared__ int colidx[64];
    __shared__ int rowidx[64];
    __shared__ unsigned char starts[64];
    __shared__ int nruns_s, nvalid_s;

    const int tid = threadIdx.x;

    // XCD-bijective swizzle: consecutive sorted tiles -> same XCD L2
    const int nwg = gridDim.x, orig = blockIdx.x;
    const int q = nwg >> 3, rr = nwg & 7, xcd = orig & 7;
    const int wgid = (xcd < rr ? xcd * (q + 1) : rr * (q + 1) + (xcd - rr) * q) + (orig >> 3);
    const int e0 = wgid * 64;

    if (tid < 64) {
        int idx = e0 + tid;
        int2 p = (idx < E) ? spair[idx] : make_int2(-1, 0);
        colidx[tid] = p.x;
        rowidx[tid] = p.y;
    }
    __syncthreads();

    if (tid < 64) {
        int c = colidx[tid];
        bool valid = (c >= 0);
        bool isStart = valid && (tid == 0 || colidx[tid - 1] != c);
        unsigned long long mb = __ballot(isStart);
        unsigned long long vb = __ballot(valid);
        if (tid == 0) { nruns_s = __popcll(mb); nvalid_s = __popcll(vb); }
        if (isStart) starts[__popcll(mb & ((1ull << tid) - 1ull))] = (unsigned char)tid;
    }

    // ---- phase 1: h = relu(Pa'[col] + Pb[row]) -> Hs (fp16, swizzled), all packed math
    ushort* Hs = (ushort*)smem;
    {
        const int cg   = tid & 15;      // 16 threads per edge -> coalesced 256B per side
        const int esub = tid >> 4;
        const f16x8 zero = {0, 0, 0, 0, 0, 0, 0, 0};
        f16x8 va[4], vb[4];
        #pragma unroll
        for (int it = 0; it < 4; ++it) {
            int e = it * 16 + esub;
            int c = colidx[e]; if (c < 0) c = 0;
            int r = rowidx[e];
            va[it] = *(const f16x8*)(pab + (size_t)c * NCH + cg * 8);
            vb[it] = *(const f16x8*)(pab + (size_t)r * NCH + 128 + cg * 8);
        }
        #pragma unroll
        for (int it = 0; it < 4; ++it) {
            int e = it * 16 + esub;
            f16x8 h = va[it] + vb[it];
            h = __builtin_elementwise_max(h, zero);
            *(f16x8*)((char*)Hs + e * 256 + ((cg * 16) ^ ((e & 7) << 4))) = h;
        }
    }
    __syncthreads();

    const int l = tid & 63, w = tid >> 6;
    const int wr = w >> 1, wc = w & 1;
    const int l15 = l & 15, lq = l >> 4;
    const int mr = wr * 32;

    // ---- layer 2: [64x128] @ [128x128] -> msg
    f32x4 acc2[2][4];
    #pragma unroll
    for (int mf = 0; mf < 2; ++mf)
        #pragma unroll
        for (int nf = 0; nf < 4; ++nf)
            acc2[mf][nf] = (f32x4){0.f, 0.f, 0.f, 0.f};

    #pragma unroll
    for (int kk = 0; kk < 4; ++kk) {
        f16x8 a[2], b[4];
        #pragma unroll
        for (int mf = 0; mf < 2; ++mf) {
            int row = mr + mf * 16 + l15;
            a[mf] = *(const f16x8*)((const char*)Hs + row * 256 + ((kk * 64 + lq * 16) ^ ((row & 7) << 4)));
        }
        #pragma unroll
        for (int nf = 0; nf < 4; ++nf) {
            int wcol = wc * 64 + nf * 16 + l15;
            b[nf] = *(const f16x8*)(w2t + wcol * 128 + kk * 32 + lq * 8);
        }
        #pragma unroll
        for (int mf = 0; mf < 2; ++mf)
            #pragma unroll
            for (int nf = 0; nf < 4; ++nf)
                acc2[mf][nf] = __builtin_amdgcn_mfma_f32_16x16x32_f16(a[mf], b[nf], acc2[mf][nf], 0, 0, 0);
    }

    // ---- two col-halves: stage M (f32, swizzled, overlaying Hs), segmented max, atomic per (run,col)
    float* Mf = (float*)smem;
    #pragma unroll
    for (int half = 0; half < 2; ++half) {
        __syncthreads();                 // all reads of smem from previous phase done
        if (wc == half) {
            #pragma unroll
            for (int nf = 0; nf < 4; ++nf)
                #pragma unroll
                for (int mf = 0; mf < 2; ++mf)
                    #pragma unroll
                    for (int r = 0; r < 4; ++r) {
                        int row = mr + mf * 16 + lq * 4 + r;
                        int cl = nf * 16 + l15;
                        *(float*)((char*)Mf + row * 256 + ((cl * 4) ^ ((row & 7) << 4))) =
                            acc2[mf][nf][r];
                    }
        }
        __syncthreads();
        {
            const int c = tid & 63, g = tid >> 6;
            const int nruns = nruns_s, nvalid = nvalid_s;
            for (int k = g; k < nruns; k += 4) {
                int s  = starts[k];
                int e_ = (k + 1 < nruns) ? (int)starts[k + 1] : nvalid;
                float m = -INFINITY;
                for (int r2 = s; r2 < e_; ++r2)
                    m = fmaxf(m, *(const float*)((const char*)Mf + r2 * 256 + ((c * 4) ^ ((r2 & 7) << 4))));
                int node = colidx[s];
                unsigned bs = __float_as_uint(m);
                unsigned enc = (bs & 0x80000000u) ? ~bs : (bs | 0x80000000u);
                atomicMax(&out_enc[(size_t)node * D + half * 64 + c], enc);
            }
        }
    }
}

// ---------- decode: in-place on d_out; u==0 -> 0.0f (empty), else decode + b2[channel]
__global__ void decode_kernel(unsigned int* __restrict__ io, const float* __restrict__ b2, int n4)
{
    int gid = blockIdx.x * blockDim.x + threadIdx.x;
    if (gid < n4) {
        uint4 u = ((const uint4*)io)[gid];
        float4 bb = ((const float4*)b2)[gid & 31];
        float4 f;
        #define DEC(ux, b) ((ux) == 0u ? 0.f : ((((ux) & 0x80000000u) ? __uint_as_float((ux) & 0x7fffffffu) : __uint_as_float(~(ux))) + (b)))
        f.x = DEC(u.x, bb.x); f.y = DEC(u.y, bb.y); f.z = DEC(u.z, bb.z); f.w = DEC(u.w, bb.w);
        #undef DEC
        ((float4*)io)[gid] = f;
    }
}

extern "C" void kernel_launch(void* const* d_in, const int* in_sizes, int n_in,
                              void* d_out, int out_size, void* d_ws, size_t ws_size,
                              hipStream_t stream)
{
    const float* x  = (const float*)d_in[0];
    const int* eidx = (const int*)d_in[1];
    const float* W1 = (const float*)d_in[2];
    const float* b1 = (const float*)d_in[3];
    const float* W2 = (const float*)d_in[4];
    const float* b2 = (const float*)d_in[5];

    const int n_nodes = in_sizes[0] / D;
    const int E = in_sizes[1] / 2;
    const int* erow = eidx;        // edge_index[0]
    const int* ecol = eidx + E;    // edge_index[1]

    // ---- workspace layout
    char* ws = (char*)d_ws;
    size_t off = 0;
    ushort* pab = (ushort*)(ws + off);   off += (size_t)n_nodes * NCH * sizeof(ushort);
    off = (off + 255) & ~(size_t)255;
    ushort* w1abt = (ushort*)(ws + off); off += (size_t)NCH * D * sizeof(ushort);
    ushort* w2t = (ushort*)(ws + off);   off += (size_t)D * D * sizeof(ushort);
    off = (off + 255) & ~(size_t)255;
    int* hist = (int*)(ws + off);        off += (size_t)n_nodes * 4;
    off = (off + 255) & ~(size_t)255;
    int* ofs = (int*)(ws + off);         off += (size_t)n_nodes * 4;
    off = (off + 255) & ~(size_t)255;
    int* partial = (int*)(ws + off);     off += 256 * 4;
    int* bofs = (int*)(ws + off);        off += 256 * 4;
    off = (off + 255) & ~(size_t)255;
    int2* spair = (int2*)(ws + off);     off += (size_t)E * 8;

    unsigned int* out_enc = (unsigned int*)d_out;

    hipMemsetAsync(d_out, 0, (size_t)out_size * sizeof(float), stream);
    hipMemsetAsync(hist, 0, (size_t)n_nodes * sizeof(int), stream);

    const int prep_work = NCH * D + D * D + E;
    prep_kernel<<<(prep_work + 255) / 256, 256, 0, stream>>>(W1, W2, ecol, w1abt, w2t, hist, E, n_nodes);

    const int nb = (n_nodes + 255) / 256;   // 196 <= 256
    scan1_kernel<<<nb, 256, 0, stream>>>(hist, partial, n_nodes);
    scan2_kernel<<<1, 256, 0, stream>>>(partial, bofs, nb);
    scan3_kernel<<<nb, 256, 0, stream>>>(hist, bofs, ofs, n_nodes);

    scatter_kernel<<<(E + 255) / 256, 256, 0, stream>>>(erow, ecol, ofs, spair, E, n_nodes);

    pab_kernel<<<(n_nodes + 63) / 64, 256, 0, stream>>>(x, w1abt, b1, pab, n_nodes);

    const int nblocks = (E + 63) / 64;
    edgeconv_main<<<nblocks, 256, 0, stream>>>(pab, w2t, spair, out_enc, E, n_nodes);

    const int n4 = out_size / 4;
    decode_kernel<<<(n4 + 255) / 256, 256, 0, stream>>>(out_enc, b2, n4);
}